// Round 1
// baseline (194.482 us; speedup 1.0000x reference)
//
#include <hip/hip_runtime.h>

// Problem constants (from reference setup_inputs):
//   messages: [B=64, E=4096, D=128] f32
//   tgt_indices: [B, E] int32 in [0, N)
//   out: [B, N=512, D] f32  (segment sum)
constexpr int B = 64, E = 4096, N = 512, D = 128;
constexpr int NT = 128;               // n-rows of output owned per block
constexpr int NBPB = N / NT;          // 4 blocks per batch
constexpr int THREADS = 512;          // 8 waves
constexpr int WAVES = THREADS / 64;

__global__ __launch_bounds__(THREADS, 1)
void seg_scatter_kernel(const float* __restrict__ msgs,
                        const int* __restrict__ tgt,
                        float* __restrict__ out) {
    __shared__ float acc[NT * D];     // 64 KiB output slab accumulator
    __shared__ int   list[E];         // 16 KiB compacted matching-edge list
    __shared__ int   count;

    const int tid  = threadIdx.x;
    const int lane = tid & 63;
    const int wave = tid >> 6;
    const int b    = blockIdx.x / NBPB;
    const int n0   = (blockIdx.x % NBPB) * NT;

    // ---- zero accumulator (float4) ----
    float4* acc4 = reinterpret_cast<float4*>(acc);
    #pragma unroll
    for (int i = 0; i < (NT * D / 4) / THREADS; ++i)
        acc4[i * THREADS + tid] = make_float4(0.f, 0.f, 0.f, 0.f);
    if (tid == 0) count = 0;
    __syncthreads();

    // ---- Phase A: scan this batch's indices, ballot-compact matches ----
    const int* tb = tgt + b * E;
    #pragma unroll
    for (int r = 0; r < E / THREADS; ++r) {
        const int e    = r * THREADS + tid;       // coalesced index read
        const int nrel = tb[e] - n0;
        const bool match = (unsigned)nrel < (unsigned)NT;
        const unsigned long long mask = __ballot(match);
        if (mask) {
            const int leader = __builtin_ctzll(mask);
            int base = 0;
            if (lane == leader) base = atomicAdd(&count, (int)__popcll(mask));
            base = __shfl(base, leader);
            if (match) {
                const int lpos = (int)__popcll(mask & ((1ull << lane) - 1ull));
                list[base + lpos] = (nrel << 16) | e;  // pack nrel(7b) | e(12b)
            }
        }
    }
    __syncthreads();
    const int cnt = count;

    // ---- Phase B: accumulate matched rows into LDS slab ----
    // Each wave takes 8 consecutive edges per iteration -> 8 independent
    // 512B row loads in flight (MLP to hide ~900cy HBM latency).
    const float* mb = msgs + (size_t)b * E * D;
    constexpr int UNROLL = 8;
    for (int k0 = wave * UNROLL; k0 < cnt; k0 += WAVES * UNROLL) {
        int   pk[UNROLL];
        float m0[UNROLL], m1[UNROLL];
        #pragma unroll
        for (int j = 0; j < UNROLL; ++j)
            if (k0 + j < cnt) pk[j] = list[k0 + j];   // wave-uniform broadcast
        #pragma unroll
        for (int j = 0; j < UNROLL; ++j)
            if (k0 + j < cnt) {
                const float* row = mb + (size_t)(pk[j] & 0xFFFF) * D;
                m0[j] = row[lane];        // 256B coalesced
                m1[j] = row[lane + 64];   // 256B coalesced
            }
        #pragma unroll
        for (int j = 0; j < UNROLL; ++j)
            if (k0 + j < cnt) {
                const int nrel = pk[j] >> 16;
                // lane-stride-1 -> 2-way bank alias only (free)
                atomicAdd(&acc[nrel * D + lane],      m0[j]);
                atomicAdd(&acc[nrel * D + lane + 64], m1[j]);
            }
    }
    __syncthreads();

    // ---- Epilogue: write the slab (covers all outputs exactly once) ----
    float4* ob = reinterpret_cast<float4*>(out + ((size_t)b * N + n0) * D);
    const float4* a4 = reinterpret_cast<const float4*>(acc);
    #pragma unroll
    for (int i = 0; i < (NT * D / 4) / THREADS; ++i)
        ob[i * THREADS + tid] = a4[i * THREADS + tid];
}

extern "C" void kernel_launch(void* const* d_in, const int* in_sizes, int n_in,
                              void* d_out, int out_size, void* d_ws, size_t ws_size,
                              hipStream_t stream) {
    const float* msgs = (const float*)d_in[0];
    const int*   tgt  = (const int*)d_in[1];
    // d_in[2] (atom_features_ref) is shape-only in the reference; unused.
    float* out = (float*)d_out;
    seg_scatter_kernel<<<B * NBPB, THREADS, 0, stream>>>(msgs, tgt, out);
}

// Round 2
// 41.976 us; speedup vs baseline: 4.6331x; 4.6331x over previous
//
#include <hip/hip_runtime.h>

// messages: [B=64, E=4096, D=128] f32 ; tgt: [B,E] int32 in [0,N=512)
// out: [B, N, D] f32 segment-sum.
constexpr int B = 64, E = 4096, N = 512, D = 128;
constexpr int SEGS = B * N;          // 32768 output rows
constexpr int CAP  = 64;             // bucket capacity (lambda=8; overflow p~1e-29)

// ---------------- pipeline kernels ----------------

__global__ void zero_counts(int* __restrict__ cnt) {
    int i = blockIdx.x * blockDim.x + threadIdx.x;
    if (i < SEGS) cnt[i] = 0;
}

__global__ void bin_edges(const int* __restrict__ tgt,
                          int* __restrict__ cnt,
                          int* __restrict__ buckets) {
    int i = blockIdx.x * blockDim.x + threadIdx.x;      // i = b*E + e
    if (i >= B * E) return;
    const int b = i >> 12;                              // E = 4096
    const int e = i & (E - 1);
    const int seg = b * N + tgt[i];
    const int slot = atomicAdd(&cnt[seg], 1);
    if (slot < CAP) buckets[(size_t)seg * CAP + slot] = e;
}

// One wave per output row; register accumulation; no LDS, no atomics.
__global__ __launch_bounds__(256)
void gather_rows(const float* __restrict__ msgs,
                 const int* __restrict__ cnt,
                 const int* __restrict__ buckets,
                 float* __restrict__ out) {
    const int lane = threadIdx.x & 63;
    const int wave = threadIdx.x >> 6;
    const int seg  = blockIdx.x * 4 + wave;
    if (seg >= SEGS) return;

    const int b = seg >> 9;                             // N = 512
    const int k = min(cnt[seg], CAP);

    // lane i holds edge id i (0-padded; padded lanes weighted out below)
    int eidx = 0;
    if (lane < k) eidx = buckets[(size_t)seg * CAP + lane];

    const float* mb = msgs + (size_t)b * E * D;
    float a0 = 0.f, a1 = 0.f;
    for (int i = 0; i < k; i += 2) {
        const int e0 = __shfl(eidx, i);
        const int e1 = __shfl(eidx, i + 1);             // may be pad (row 0)
        const float w1 = (i + 1 < k) ? 1.f : 0.f;
        const float* r0 = mb + (size_t)e0 * D;
        const float* r1 = mb + (size_t)e1 * D;
        // 4 independent 256B coalesced loads in flight
        const float x0 = r0[lane], x1 = r0[lane + 64];
        const float y0 = r1[lane], y1 = r1[lane + 64];
        a0 += x0;      a1 += x1;
        a0 += w1 * y0; a1 += w1 * y1;
    }
    float* o = out + (size_t)seg * D;                   // covers every output
    o[lane]      = a0;
    o[lane + 64] = a1;
}

// ---------------- fallback (if ws too small): global-atomic scatter ----------------

__global__ void zero_out(float* __restrict__ out) {
    int i = blockIdx.x * blockDim.x + threadIdx.x;
    if (i < SEGS * D) out[i] = 0.f;
}

__global__ void scatter_atomic(const float* __restrict__ msgs,
                               const int* __restrict__ tgt,
                               float* __restrict__ out) {
    const int lane = threadIdx.x & 63;
    const int wave = threadIdx.x >> 6;
    const int edge = blockIdx.x * 4 + wave;             // b*E + e
    if (edge >= B * E) return;
    const int b = edge >> 12;
    const int seg = b * N + tgt[edge];
    const float* r = msgs + (size_t)edge * D;
    float* o = out + (size_t)seg * D;
    atomicAdd(&o[lane],      r[lane]);
    atomicAdd(&o[lane + 64], r[lane + 64]);
}

// ---------------- launch ----------------

extern "C" void kernel_launch(void* const* d_in, const int* in_sizes, int n_in,
                              void* d_out, int out_size, void* d_ws, size_t ws_size,
                              hipStream_t stream) {
    const float* msgs = (const float*)d_in[0];
    const int*   tgt  = (const int*)d_in[1];
    float* out = (float*)d_out;

    const size_t need = (size_t)SEGS * sizeof(int)              // counters
                      + (size_t)SEGS * CAP * sizeof(int);       // buckets
    if (ws_size >= need) {
        int* cnt     = (int*)d_ws;
        int* buckets = cnt + SEGS;
        zero_counts<<<(SEGS + 255) / 256, 256, 0, stream>>>(cnt);
        bin_edges<<<(B * E + 255) / 256, 256, 0, stream>>>(tgt, cnt, buckets);
        gather_rows<<<SEGS / 4, 256, 0, stream>>>(msgs, cnt, buckets, out);
    } else {
        zero_out<<<(SEGS * D + 255) / 256, 256, 0, stream>>>(out);
        scatter_atomic<<<B * E / 4, 256, 0, stream>>>(msgs, tgt, out);
    }
}

// Round 3
// 41.184 us; speedup vs baseline: 4.7222x; 1.0192x over previous
//
#include <hip/hip_runtime.h>

// messages: [B=64, E=4096, D=128] f32 ; tgt: [B,E] int32 in [0,N=512)
// out: [B, N, D] f32 segment-sum.
constexpr int B = 64, E = 4096, N = 512, D = 128;
constexpr int SEGS = B * N;          // 32768 output rows
constexpr int CAP  = 64;             // bucket capacity (lambda=8; overflow p~1e-29)

// ---------------- pipeline kernels ----------------

// Grid exact: B*E/256 blocks. One edge per thread.
__global__ __launch_bounds__(256)
void bin_edges(const int* __restrict__ tgt,
               int* __restrict__ cnt,
               unsigned short* __restrict__ bkt) {
    const int i = blockIdx.x * 256 + threadIdx.x;       // i = b*E + e
    const int b = i >> 12;                              // E = 4096
    const int e = i & (E - 1);
    const int seg = b * N + tgt[i];
    const int slot = atomicAdd(&cnt[seg], 1);
    if (slot < CAP) bkt[(size_t)seg * CAP + slot] = (unsigned short)e;
}

// One wave per output row. float2 lane loads (512B/row in ONE instr),
// 4-edge unroll -> 4 independent row loads in flight. No LDS, no atomics.
__global__ __launch_bounds__(256)
void gather_rows(const float* __restrict__ msgs,
                 const int* __restrict__ cnt,
                 const unsigned short* __restrict__ bkt,
                 float* __restrict__ out) {
    const int lane = threadIdx.x & 63;
    const int wave = threadIdx.x >> 6;
    const int seg  = blockIdx.x * 4 + wave;             // grid exact: SEGS/4
    const int b    = seg >> 9;                          // N = 512
    const int k    = min(cnt[seg], CAP);

    // lane i holds edge id i (0-padded; pads weighted out below)
    const int eidx = (lane < k) ? (int)bkt[(size_t)seg * CAP + lane] : 0;

    const float2* mb = reinterpret_cast<const float2*>(msgs) + (size_t)b * E * 64;
    float ax = 0.f, ay = 0.f;
    for (int i = 0; i < k; i += 4) {
        const int e0 = __shfl(eidx, i);
        const int e1 = __shfl(eidx, i + 1);
        const int e2 = __shfl(eidx, i + 2);
        const int e3 = __shfl(eidx, i + 3);
        const float w1 = (i + 1 < k) ? 1.f : 0.f;
        const float w2 = (i + 2 < k) ? 1.f : 0.f;
        const float w3 = (i + 3 < k) ? 1.f : 0.f;
        // 4 independent 512B coalesced loads (dwordx2 per lane)
        const float2 x0 = mb[(size_t)e0 * 64 + lane];
        const float2 x1 = mb[(size_t)e1 * 64 + lane];
        const float2 x2 = mb[(size_t)e2 * 64 + lane];
        const float2 x3 = mb[(size_t)e3 * 64 + lane];
        ax += x0.x;      ay += x0.y;
        ax += w1 * x1.x; ay += w1 * x1.y;
        ax += w2 * x2.x; ay += w2 * x2.y;
        ax += w3 * x3.x; ay += w3 * x3.y;
    }
    float2 r; r.x = ax; r.y = ay;
    reinterpret_cast<float2*>(out)[(size_t)seg * 64 + lane] = r;  // covers all outputs
}

// ---------------- fallback (if ws too small): global-atomic scatter ----------------

__global__ void zero_out(float* __restrict__ out) {
    int i = blockIdx.x * blockDim.x + threadIdx.x;
    if (i < SEGS * D) out[i] = 0.f;
}

__global__ void scatter_atomic(const float* __restrict__ msgs,
                               const int* __restrict__ tgt,
                               float* __restrict__ out) {
    const int lane = threadIdx.x & 63;
    const int wave = threadIdx.x >> 6;
    const int edge = blockIdx.x * 4 + wave;             // b*E + e
    if (edge >= B * E) return;
    const int b = edge >> 12;
    const int seg = b * N + tgt[edge];
    const float* r = msgs + (size_t)edge * D;
    float* o = out + (size_t)seg * D;
    atomicAdd(&o[lane],      r[lane]);
    atomicAdd(&o[lane + 64], r[lane + 64]);
}

// ---------------- launch ----------------

extern "C" void kernel_launch(void* const* d_in, const int* in_sizes, int n_in,
                              void* d_out, int out_size, void* d_ws, size_t ws_size,
                              hipStream_t stream) {
    const float* msgs = (const float*)d_in[0];
    const int*   tgt  = (const int*)d_in[1];
    float* out = (float*)d_out;

    const size_t need = (size_t)SEGS * sizeof(int)                  // counters
                      + (size_t)SEGS * CAP * sizeof(unsigned short);// u16 buckets
    if (ws_size >= need) {
        int* cnt = (int*)d_ws;
        unsigned short* bkt = (unsigned short*)(cnt + SEGS);
        hipMemsetAsync(cnt, 0, SEGS * sizeof(int), stream);         // capture-safe memset node
        bin_edges<<<B * E / 256, 256, 0, stream>>>(tgt, cnt, bkt);
        gather_rows<<<SEGS / 4, 256, 0, stream>>>(msgs, cnt, bkt, out);
    } else {
        zero_out<<<(SEGS * D + 255) / 256, 256, 0, stream>>>(out);
        scatter_atomic<<<B * E / 4, 256, 0, stream>>>(msgs, tgt, out);
    }
}

// Round 4
// 32.811 us; speedup vs baseline: 5.9274x; 1.2552x over previous
//
#include <hip/hip_runtime.h>

// messages: [B=64, E=4096, D=128] f32 ; tgt: [B,E] int32 in [0,N=512)
// out: [B, N, D] f32 segment-sum.
constexpr int B = 64, E = 4096, N = 512, D = 128;
constexpr int SEGS = B * N;
constexpr int GOFFS = 520;   // u16 stride of per-batch offset table (513 used)

// ---- Kernel 1: per-batch CSR binning, LDS-only, no global atomics ----
// One block per batch. Coalesced global writes only.
__global__ __launch_bounds__(1024)
void bin_edges_csr(const int* __restrict__ tgt,
                   unsigned short* __restrict__ goff,
                   unsigned short* __restrict__ gcsr) {
    __shared__ int lcur[N];               // counts -> placement cursors
    __shared__ int wsum[8];
    __shared__ unsigned short lst[E];     // 8 KiB seg-sorted edge list

    const int tid  = threadIdx.x;
    const int lane = tid & 63;
    const int w    = tid >> 6;
    const int b    = blockIdx.x;
    const int* tb  = tgt + b * E;

    if (tid < N) lcur[tid] = 0;
    __syncthreads();

    // pass 1: count (keep targets in regs for pass 2)
    int tn[4];
    #pragma unroll
    for (int t = 0; t < 4; ++t) {
        tn[t] = tb[t * 1024 + tid];       // coalesced
        atomicAdd(&lcur[tn[t]], 1);
    }
    __syncthreads();

    // exclusive scan of lcur[0..511]: shfl intra-wave + 8-wave combine
    int c = (tid < N) ? lcur[tid] : 0;
    int x = c;
    #pragma unroll
    for (int d = 1; d < 64; d <<= 1) {
        int y = __shfl_up(x, d);
        if (lane >= d) x += y;
    }
    if (tid < N && lane == 63) wsum[w] = x;   // wave totals (waves 0..7)
    __syncthreads();
    if (tid == 0) {
        int s = 0;
        #pragma unroll
        for (int i = 0; i < 8; ++i) { int t = wsum[i]; wsum[i] = s; s += t; }
    }
    __syncthreads();
    if (tid < N) {
        const int excl = x - c + wsum[w];
        lcur[tid] = excl;                          // placement cursor
        goff[b * GOFFS + tid] = (unsigned short)excl;
    }
    if (tid == 0) goff[b * GOFFS + N] = (unsigned short)E;  // total is always E
    __syncthreads();

    // pass 2: place edge ids (LDS atomics only)
    #pragma unroll
    for (int t = 0; t < 4; ++t) {
        const int e = t * 1024 + tid;
        const int pos = atomicAdd(&lcur[tn[t]], 1);
        lst[pos] = (unsigned short)e;
    }
    __syncthreads();

    // coalesced CSR writeout (uint = 2 ids per store)
    const unsigned int* l32 = reinterpret_cast<const unsigned int*>(lst);
    unsigned int* g32 = reinterpret_cast<unsigned int*>(gcsr + (size_t)b * E);
    #pragma unroll
    for (int t = 0; t < 2; ++t) g32[t * 1024 + tid] = l32[t * 1024 + tid];
}

// ---- Kernel 2: one wave per output row; contiguous CSR ids; 8-deep MLP ----
__global__ __launch_bounds__(256)
void gather_rows(const float* __restrict__ msgs,
                 const unsigned short* __restrict__ goff,
                 const unsigned short* __restrict__ gcsr,
                 float* __restrict__ out) {
    const int lane = threadIdx.x & 63;
    const int wave = threadIdx.x >> 6;
    const int seg  = blockIdx.x * 4 + wave;        // grid exact: SEGS/4
    const int b    = seg >> 9;                     // N = 512
    const int n    = seg & (N - 1);

    const unsigned short* ob = goff + b * GOFFS + n;
    const int base = ob[0];
    const int k    = (int)ob[1] - base;
    const unsigned short* cb = gcsr + (size_t)b * E + base;   // contiguous ids
    const float2* mb = reinterpret_cast<const float2*>(msgs) + (size_t)b * E * 64;

    float ax = 0.f, ay = 0.f;
    for (int c0 = 0; c0 < k; c0 += 64) {           // one iter unless k > 64
        const int kk = min(k - c0, 64);
        const int eidx = (lane < kk) ? (int)cb[c0 + lane] : 0;
        for (int i = 0; i < kk; i += 8) {
            int ee[8]; float ww[8];
            #pragma unroll
            for (int j = 0; j < 8; ++j) {
                ee[j] = __shfl(eidx, i + j);
                ww[j] = (i + j < kk) ? 1.f : 0.f;
            }
            float2 v[8];
            #pragma unroll
            for (int j = 0; j < 8; ++j)            // 8 independent 512B loads
                v[j] = mb[(size_t)ee[j] * 64 + lane];
            #pragma unroll
            for (int j = 0; j < 8; ++j) { ax += ww[j] * v[j].x; ay += ww[j] * v[j].y; }
        }
    }
    float2 r; r.x = ax; r.y = ay;
    reinterpret_cast<float2*>(out)[(size_t)seg * 64 + lane] = r;   // covers all outputs
}

// ---------------- fallback (ws too small): global-atomic scatter ----------------

__global__ void zero_out(float* __restrict__ out) {
    int i = blockIdx.x * blockDim.x + threadIdx.x;
    if (i < SEGS * D) out[i] = 0.f;
}

__global__ void scatter_atomic(const float* __restrict__ msgs,
                               const int* __restrict__ tgt,
                               float* __restrict__ out) {
    const int lane = threadIdx.x & 63;
    const int wave = threadIdx.x >> 6;
    const int edge = blockIdx.x * 4 + wave;
    if (edge >= B * E) return;
    const int b = edge >> 12;
    const int seg = b * N + tgt[edge];
    const float* r = msgs + (size_t)edge * D;
    float* o = out + (size_t)seg * D;
    atomicAdd(&o[lane],      r[lane]);
    atomicAdd(&o[lane + 64], r[lane + 64]);
}

// ---------------- launch ----------------

extern "C" void kernel_launch(void* const* d_in, const int* in_sizes, int n_in,
                              void* d_out, int out_size, void* d_ws, size_t ws_size,
                              hipStream_t stream) {
    const float* msgs = (const float*)d_in[0];
    const int*   tgt  = (const int*)d_in[1];
    float* out = (float*)d_out;

    const size_t need = (size_t)B * GOFFS * sizeof(unsigned short)   // offsets
                      + (size_t)B * E * sizeof(unsigned short);      // CSR ids
    if (ws_size >= need) {
        unsigned short* goff = (unsigned short*)d_ws;
        unsigned short* gcsr = goff + (size_t)B * GOFFS;
        bin_edges_csr<<<B, 1024, 0, stream>>>(tgt, goff, gcsr);
        gather_rows<<<SEGS / 4, 256, 0, stream>>>(msgs, goff, gcsr, out);
    } else {
        zero_out<<<(SEGS * D + 255) / 256, 256, 0, stream>>>(out);
        scatter_atomic<<<B * E / 4, 256, 0, stream>>>(msgs, tgt, out);
    }
}